// Round 1
// 1522.666 us; speedup vs baseline: 1.4277x; 1.4277x over previous
//
#include <hip/hip_runtime.h>
#include <stdint.h>

#define N_TOKENS 8192
#define D_IN 4096
#define D_OUT 12288

#define BM 128
#define BN 128
#define BK 64

typedef float floatx4 __attribute__((ext_vector_type(4)));

__device__ __forceinline__ float clamp448(float v) {
  return fminf(fmaxf(v, -448.0f), 448.0f);
}

__device__ __forceinline__ uint32_t pack_fp8x4(float a, float b, float c, float d) {
  // v_cvt_pk_fp8_f32: RNE, OCP e4m3fn on gfx950
  int p = __builtin_amdgcn_cvt_pk_fp8_f32(a, b, 0, false);
  p = __builtin_amdgcn_cvt_pk_fp8_f32(c, d, p, true);
  return (uint32_t)p;
}

// ---------------------------------------------------------------------------
// Kernel 1: add_out = x + residual; inv_rms over row; q = fp8(add*inv_rms*nw/is)
// one block (256 thr) per row of 4096
// ---------------------------------------------------------------------------
__global__ __launch_bounds__(256) void fused_norm_quant(
    const float* __restrict__ x, const float* __restrict__ res,
    const float* __restrict__ nw, const float* __restrict__ inscale,
    float* __restrict__ add_out, uint32_t* __restrict__ act8) {
  const int row = blockIdx.x;
  const int t = threadIdx.x;
  const float4* xr = (const float4*)(x + (size_t)row * D_IN);
  const float4* rr = (const float4*)(res + (size_t)row * D_IN);
  float4* ar = (float4*)(add_out + (size_t)row * D_IN);

  float4 v[4];
  float ss = 0.f;
#pragma unroll
  for (int i = 0; i < 4; ++i) {
    const int idx = t + i * 256;
    float4 a = xr[idx];
    float4 b = rr[idx];
    float4 s;
    s.x = a.x + b.x; s.y = a.y + b.y; s.z = a.z + b.z; s.w = a.w + b.w;
    v[i] = s;
    ar[idx] = s;
    ss += s.x * s.x + s.y * s.y + s.z * s.z + s.w * s.w;
  }
#pragma unroll
  for (int off = 32; off > 0; off >>= 1) ss += __shfl_down(ss, off, 64);
  __shared__ float wred[4];
  if ((t & 63) == 0) wred[t >> 6] = ss;
  __syncthreads();
  const float total = wred[0] + wred[1] + wred[2] + wred[3];
  // precise rsqrt path to match np reference rounding as closely as possible
  const float inv_rms = 1.0f / sqrtf(total * (1.0f / D_IN) + 1e-5f);
  const float f = inv_rms / inscale[0];

  const float4* wr = (const float4*)nw;
#pragma unroll
  for (int i = 0; i < 4; ++i) {
    const int idx = t + i * 256;
    float4 w = wr[idx];
    float4 s = v[i];
    uint32_t p = pack_fp8x4(clamp448(s.x * f * w.x), clamp448(s.y * f * w.y),
                            clamp448(s.z * f * w.z), clamp448(s.w * f * w.w));
    act8[(size_t)row * (D_IN / 4) + idx] = p;
  }
}

// ---------------------------------------------------------------------------
// Kernel 2: w (f32 values exactly on e4m3 grid) -> e4m3 bytes (exact)
// ---------------------------------------------------------------------------
__global__ __launch_bounds__(256) void w_quant(const float4* __restrict__ w,
                                               uint32_t* __restrict__ w8) {
  const size_t i = (size_t)blockIdx.x * 256 + threadIdx.x;
  float4 v = w[i];
  w8[i] = pack_fp8x4(v.x, v.y, v.z, v.w);
}

// ---------------------------------------------------------------------------
// Kernel 3: C[M][N] = A[M][K] * B[N][K]^T, fp8 e4m3 inputs, f32 out, * scale
// m97-style: 128x128 tile, BK=64, global_load_lds x16, 16x16x32 fp8 MFMA
//
// LDS swizzle (T2, rule #21 both-sides): 16B-chunk index c of row r is stored
// at phys chunk c ^ ((r>>1)&3).  Applied on the GLOBAL source address at stage
// time (global_load_lds dest must stay linear) and on the LDS read address.
// Read-side XOR collapses to the per-lane constant (l16>>1)&3 (wm/2 and 8i are
// both ≡0 mod 4), so the K-loop body is unchanged except a precomputed offset.
// Bank math: before — 64 lanes on 16 banks, 8 dwords/bank (16 cyc vs 4 floor);
// after  — uniform 4 dwords/bank = conflict-free floor.
// ---------------------------------------------------------------------------
__global__ __launch_bounds__(256) void gemm_fp8(
    const uint8_t* __restrict__ A, const uint8_t* __restrict__ B,
    const float* __restrict__ inscale, const float* __restrict__ wscale,
    float* __restrict__ C) {
  __shared__ __align__(16) uint8_t sA[BM * BK];
  __shared__ __align__(16) uint8_t sB[BN * BK];
  const int t = threadIdx.x;
  const int m0 = blockIdx.y * BM;
  const int n0 = blockIdx.x * BN;
  const int lane = t & 63;
  const int wave = t >> 6;
  const int wm = (wave >> 1) * 64;  // wave row offset in tile
  const int wn = (wave & 1) * 64;   // wave col offset in tile
  const int quad = lane >> 4;
  const int l16 = lane & 15;

  floatx4 acc[4][4] = {};

  // staging: thread t fills LDS row t>>2, phys 16B chunk t&3.
  // source global chunk = (t&3) ^ x(row), x(row) = (row>>1)&3 = (t>>3)&3
  // (same for the +64-row half: (64+u)>>1 = 32+(u>>1), 32≡0 mod 4).
  const int csrc = ((t & 3) ^ ((t >> 3) & 3)) * 16;
  const uint8_t* ag0 = A + (size_t)(m0 + (t >> 2)) * D_IN + csrc;
  const uint8_t* ag1 = ag0 + (size_t)64 * D_IN;
  const uint8_t* bg0 = B + (size_t)(n0 + (t >> 2)) * D_IN + csrc;
  const uint8_t* bg1 = bg0 + (size_t)64 * D_IN;

  uint8_t* la0 = sA + t * 16;
  uint8_t* la1 = sA + 4096 + t * 16;
  uint8_t* lb0 = sB + t * 16;
  uint8_t* lb1 = sB + 4096 + t * 16;

  // read side: logical chunk (quad>>1)|(s<<1), XOR with per-lane (l16>>1)&3
  const int xorv = (l16 >> 1) & 3;
  const int qh = quad >> 1;
  const uint8_t* pa2 = sA + (size_t)(wm + l16) * BK + (quad & 1) * 8;
  const uint8_t* pb2 = sB + (size_t)(wn + l16) * BK + (quad & 1) * 8;

  for (int k = 0; k < D_IN; k += BK) {
    __builtin_amdgcn_global_load_lds(
        (const __attribute__((address_space(1))) uint32_t*)(ag0 + k),
        (__attribute__((address_space(3))) uint32_t*)la0, 16, 0, 0);
    __builtin_amdgcn_global_load_lds(
        (const __attribute__((address_space(1))) uint32_t*)(ag1 + k),
        (__attribute__((address_space(3))) uint32_t*)la1, 16, 0, 0);
    __builtin_amdgcn_global_load_lds(
        (const __attribute__((address_space(1))) uint32_t*)(bg0 + k),
        (__attribute__((address_space(3))) uint32_t*)lb0, 16, 0, 0);
    __builtin_amdgcn_global_load_lds(
        (const __attribute__((address_space(1))) uint32_t*)(bg1 + k),
        (__attribute__((address_space(3))) uint32_t*)lb1, 16, 0, 0);
    __syncthreads();
#pragma unroll
    for (int s = 0; s < 2; ++s) {
      const int cofs = ((qh | (s << 1)) ^ xorv) * 16;
      long af[4], bf[4];
#pragma unroll
      for (int i = 0; i < 4; ++i) af[i] = *(const long*)(pa2 + i * 16 * BK + cofs);
#pragma unroll
      for (int i = 0; i < 4; ++i) bf[i] = *(const long*)(pb2 + i * 16 * BK + cofs);
#pragma unroll
      for (int mi = 0; mi < 4; ++mi)
#pragma unroll
        for (int ni = 0; ni < 4; ++ni)
          acc[mi][ni] = __builtin_amdgcn_mfma_f32_16x16x32_fp8_fp8(
              af[mi], bf[ni], acc[mi][ni], 0, 0, 0);
    }
    __syncthreads();
  }

  const float sc = inscale[0] * wscale[0];
#pragma unroll
  for (int mi = 0; mi < 4; ++mi) {
#pragma unroll
    for (int ni = 0; ni < 4; ++ni) {
      const int r0 = m0 + wm + mi * 16 + quad * 4;
      const int c0 = n0 + wn + ni * 16 + l16;
#pragma unroll
      for (int r = 0; r < 4; ++r)
        C[(size_t)(r0 + r) * D_OUT + c0] = acc[mi][ni][r] * sc;
    }
  }
}

// ---------------------------------------------------------------------------
extern "C" void kernel_launch(void* const* d_in, const int* in_sizes, int n_in,
                              void* d_out, int out_size, void* d_ws, size_t ws_size,
                              hipStream_t stream) {
  const float* x = (const float*)d_in[0];
  const float* res = (const float*)d_in[1];
  const float* nw = (const float*)d_in[2];
  const float* w = (const float*)d_in[3];
  const float* is_p = (const float*)d_in[4];
  const float* ws_p = (const float*)d_in[5];

  float* out = (float*)d_out;                            // [8192][12288]
  float* add_out = out + (size_t)N_TOKENS * D_OUT;       // [8192][4096]

  uint8_t* act8 = (uint8_t*)d_ws;                        // 32 MiB
  uint8_t* w8 = act8 + (size_t)N_TOKENS * D_IN;          // 48 MiB

  fused_norm_quant<<<N_TOKENS, 256, 0, stream>>>(x, res, nw, is_p, add_out,
                                                 (uint32_t*)act8);
  w_quant<<<(D_OUT * (size_t)D_IN) / 4 / 256, 256, 0, stream>>>(
      (const float4*)w, (uint32_t*)w8);
  dim3 grid(D_OUT / BN, N_TOKENS / BM);
  gemm_fp8<<<grid, 256, 0, stream>>>(act8, w8, is_p, ws_p, out);
}

// Round 2
// 1182.094 us; speedup vs baseline: 1.8390x; 1.2881x over previous
//
#include <hip/hip_runtime.h>
#include <stdint.h>

#define N_TOKENS 8192
#define D_IN 4096
#define D_OUT 12288

#define BM 128
#define BN 128
#define BK 128

typedef float floatx4 __attribute__((ext_vector_type(4)));
typedef int intx4 __attribute__((ext_vector_type(4)));
typedef int intx8 __attribute__((ext_vector_type(8)));

__device__ __forceinline__ float clamp448(float v) {
  return fminf(fmaxf(v, -448.0f), 448.0f);
}

__device__ __forceinline__ uint32_t pack_fp8x4(float a, float b, float c, float d) {
  // v_cvt_pk_fp8_f32: RNE, OCP e4m3fn on gfx950
  int p = __builtin_amdgcn_cvt_pk_fp8_f32(a, b, 0, false);
  p = __builtin_amdgcn_cvt_pk_fp8_f32(c, d, p, true);
  return (uint32_t)p;
}

// ---------------------------------------------------------------------------
// Kernel 1: add_out = x + residual; inv_rms over row; q = fp8(add*inv_rms*nw/is)
// one block (256 thr) per row of 4096
// ---------------------------------------------------------------------------
__global__ __launch_bounds__(256) void fused_norm_quant(
    const float* __restrict__ x, const float* __restrict__ res,
    const float* __restrict__ nw, const float* __restrict__ inscale,
    float* __restrict__ add_out, uint32_t* __restrict__ act8) {
  const int row = blockIdx.x;
  const int t = threadIdx.x;
  const float4* xr = (const float4*)(x + (size_t)row * D_IN);
  const float4* rr = (const float4*)(res + (size_t)row * D_IN);
  float4* ar = (float4*)(add_out + (size_t)row * D_IN);

  float4 v[4];
  float ss = 0.f;
#pragma unroll
  for (int i = 0; i < 4; ++i) {
    const int idx = t + i * 256;
    float4 a = xr[idx];
    float4 b = rr[idx];
    float4 s;
    s.x = a.x + b.x; s.y = a.y + b.y; s.z = a.z + b.z; s.w = a.w + b.w;
    v[i] = s;
    ar[idx] = s;
    ss += s.x * s.x + s.y * s.y + s.z * s.z + s.w * s.w;
  }
#pragma unroll
  for (int off = 32; off > 0; off >>= 1) ss += __shfl_down(ss, off, 64);
  __shared__ float wred[4];
  if ((t & 63) == 0) wred[t >> 6] = ss;
  __syncthreads();
  const float total = wred[0] + wred[1] + wred[2] + wred[3];
  // precise rsqrt path to match np reference rounding as closely as possible
  const float inv_rms = 1.0f / sqrtf(total * (1.0f / D_IN) + 1e-5f);
  const float f = inv_rms / inscale[0];

  const float4* wr = (const float4*)nw;
#pragma unroll
  for (int i = 0; i < 4; ++i) {
    const int idx = t + i * 256;
    float4 w = wr[idx];
    float4 s = v[i];
    uint32_t p = pack_fp8x4(clamp448(s.x * f * w.x), clamp448(s.y * f * w.y),
                            clamp448(s.z * f * w.z), clamp448(s.w * f * w.w));
    act8[(size_t)row * (D_IN / 4) + idx] = p;
  }
}

// ---------------------------------------------------------------------------
// Kernel 2: w (f32 values exactly on e4m3 grid) -> e4m3 bytes (exact)
// ---------------------------------------------------------------------------
__global__ __launch_bounds__(256) void w_quant(const float4* __restrict__ w,
                                               uint32_t* __restrict__ w8) {
  const size_t i = (size_t)blockIdx.x * 256 + threadIdx.x;
  float4 v = w[i];
  w8[i] = pack_fp8x4(v.x, v.y, v.z, v.w);
}

// ---------------------------------------------------------------------------
// Kernel 3: C[M][N] = A[M][K] * B[N][K]^T, fp8 e4m3 inputs, f32 out, * scale
// MX-scaled path (m148): mfma_scale_f32_16x16x128_f8f6f4 with e8m0 scale=127
// (2^0 = 1.0) -> numerically identical to plain fp8 dot, 2x matrix rate.
// BK=128: one MFMA consumes a full 128B LDS row per lane-quad.
//
// LDS swizzle (rule #21 both-sides): 16B-chunk c of row r stored at phys
// chunk c ^ (r&7).  Stage side: applied on the GLOBAL source address
// (global_load_lds dest stays linear).  Read side: lane reads chunks
// 2*quad, 2*quad+1 of row l16 -> phys = chunk ^ (l16&7); all row offsets
// (wm, mi*16, 32r) are ===0 mod 8 so the XOR value is a per-lane constant.
// Bank check (ds_read_b128): 8 lanes per phys-chunk slot x 4 banks =
// 8 dword-accesses/bank = the 8-cycle wave64 floor -> conflict-free.
// ---------------------------------------------------------------------------
__global__ __launch_bounds__(256) void gemm_fp8(
    const uint8_t* __restrict__ A, const uint8_t* __restrict__ B,
    const float* __restrict__ inscale, const float* __restrict__ wscale,
    float* __restrict__ C) {
  __shared__ __align__(16) uint8_t sA[BM * BK];  // 16 KB
  __shared__ __align__(16) uint8_t sB[BN * BK];  // 16 KB
  const int t = threadIdx.x;
  const int m0 = blockIdx.y * BM;
  const int n0 = blockIdx.x * BN;
  const int lane = t & 63;
  const int wave = t >> 6;
  const int wm = (wave >> 1) * 64;  // wave row offset in tile
  const int wn = (wave & 1) * 64;   // wave col offset in tile
  const int quad = lane >> 4;
  const int l16 = lane & 15;

  floatx4 acc[4][4] = {};

  // staging: thread t fills LDS row (t>>3)+32r, phys chunk t&7 (la = sA+t*16).
  // global source chunk = (t&7) ^ (row&7); row&7 = (t>>3)&7 for all r.
  const int srow = t >> 3;
  const int csrc = ((t & 7) ^ (srow & 7)) * 16;
  const uint8_t* ag = A + (size_t)(m0 + srow) * D_IN + csrc;
  const uint8_t* bg = B + (size_t)(n0 + srow) * D_IN + csrc;
  uint8_t* la = sA + t * 16;
  uint8_t* lb = sB + t * 16;

  // read side: per-lane swizzled chunk offsets (constants)
  const int xv = l16 & 7;
  const int off0 = ((2 * quad) ^ xv) * 16;
  const int off1 = ((2 * quad + 1) ^ xv) * 16;
  const uint8_t* paL = sA + (size_t)(wm + l16) * BK + off0;
  const uint8_t* paH = sA + (size_t)(wm + l16) * BK + off1;
  const uint8_t* pbL = sB + (size_t)(wn + l16) * BK + off0;
  const uint8_t* pbH = sB + (size_t)(wn + l16) * BK + off1;

  for (int k = 0; k < D_IN; k += BK) {
#pragma unroll
    for (int r = 0; r < 4; ++r) {
      __builtin_amdgcn_global_load_lds(
          (const __attribute__((address_space(1))) uint32_t*)(ag + k + (size_t)(32 * r) * D_IN),
          (__attribute__((address_space(3))) uint32_t*)(la + r * 4096), 16, 0, 0);
      __builtin_amdgcn_global_load_lds(
          (const __attribute__((address_space(1))) uint32_t*)(bg + k + (size_t)(32 * r) * D_IN),
          (__attribute__((address_space(3))) uint32_t*)(lb + r * 4096), 16, 0, 0);
    }
    __syncthreads();

    intx8 bfv[4];
#pragma unroll
    for (int i = 0; i < 4; ++i) {
      intx4 lo = *(const intx4*)(pbL + i * 16 * BK);
      intx4 hi = *(const intx4*)(pbH + i * 16 * BK);
      bfv[i] = __builtin_shufflevector(lo, hi, 0, 1, 2, 3, 4, 5, 6, 7);
    }
#pragma unroll
    for (int mi = 0; mi < 4; ++mi) {
      intx4 lo = *(const intx4*)(paL + mi * 16 * BK);
      intx4 hi = *(const intx4*)(paH + mi * 16 * BK);
      intx8 afv = __builtin_shufflevector(lo, hi, 0, 1, 2, 3, 4, 5, 6, 7);
#pragma unroll
      for (int ni = 0; ni < 4; ++ni)
        acc[mi][ni] = __builtin_amdgcn_mfma_scale_f32_16x16x128_f8f6f4(
            afv, bfv[ni], acc[mi][ni], 0 /*A=fp8*/, 0 /*B=fp8*/, 0, 127, 0, 127);
    }
    __syncthreads();
  }

  const float sc = inscale[0] * wscale[0];
#pragma unroll
  for (int mi = 0; mi < 4; ++mi) {
#pragma unroll
    for (int ni = 0; ni < 4; ++ni) {
      const int r0 = m0 + wm + mi * 16 + quad * 4;
      const int c0 = n0 + wn + ni * 16 + l16;
#pragma unroll
      for (int r = 0; r < 4; ++r)
        C[(size_t)(r0 + r) * D_OUT + c0] = acc[mi][ni][r] * sc;
    }
  }
}

// ---------------------------------------------------------------------------
extern "C" void kernel_launch(void* const* d_in, const int* in_sizes, int n_in,
                              void* d_out, int out_size, void* d_ws, size_t ws_size,
                              hipStream_t stream) {
  const float* x = (const float*)d_in[0];
  const float* res = (const float*)d_in[1];
  const float* nw = (const float*)d_in[2];
  const float* w = (const float*)d_in[3];
  const float* is_p = (const float*)d_in[4];
  const float* ws_p = (const float*)d_in[5];

  float* out = (float*)d_out;                            // [8192][12288]
  float* add_out = out + (size_t)N_TOKENS * D_OUT;       // [8192][4096]

  uint8_t* act8 = (uint8_t*)d_ws;                        // 32 MiB
  uint8_t* w8 = act8 + (size_t)N_TOKENS * D_IN;          // 48 MiB

  fused_norm_quant<<<N_TOKENS, 256, 0, stream>>>(x, res, nw, is_p, add_out,
                                                 (uint32_t*)act8);
  w_quant<<<(D_OUT * (size_t)D_IN) / 4 / 256, 256, 0, stream>>>(
      (const float4*)w, (uint32_t*)w8);
  dim3 grid(D_OUT / BN, N_TOKENS / BM);
  gemm_fp8<<<grid, 256, 0, stream>>>(act8, w8, is_p, ws_p, out);
}